// Round 1
// baseline (1878.562 us; speedup 1.0000x reference)
//
#include <hip/hip_runtime.h>

// ---------------- problem constants ----------------
#define NPTS   100000
#define DIMD   256
#define BQ     256
#define KNB    16
#define NQROWS 4096
#define PCHUNK 128
#define NPCH   782           // ceil(100000/128)
#define NCAND  (NPCH*16)     // candidates per query for final merge
#define NS_ITERS 26
#define KSPLIT  32
#define KSLICE  3136         // 32*3136 = 100352 >= 100000

// scal[] slots
#define SC_LM   0
#define SC_TRCX 1
#define SC_TRCT 2
#define SC_FROB 3
#define SC_KNN  4
#define SC_REG  5
#define SC_LD   6

#define BIGF 3.4e38f

// ---------------- zero init ----------------
__global__ __launch_bounds__(256) void zero_kernel(float* ws) {
    int idx = blockIdx.x * 256 + threadIdx.x;
    if (idx < 66560) ws[idx] = 0.0f;   // mu_sum + scal + pad + covX accumulator
}

// ---------------- X stats: column sums (for mu_X) + row sq-norms ----------------
__global__ __launch_bounds__(256) void statsx_kernel(const float* __restrict__ X,
                                                     float* __restrict__ xsq,
                                                     float* __restrict__ mu_sum) {
    int w    = threadIdx.x >> 6;   // wave 0..3
    int lane = threadIdx.x & 63;
    int rbase = blockIdx.x * 1024;
    float cs0 = 0.f, cs1 = 0.f, cs2 = 0.f, cs3 = 0.f;
    for (int m = 0; m < 256; ++m) {
        int r = rbase + w + 4 * m;
        if (r < NPTS) {
            float4 v = *(const float4*)&X[r * DIMD + 4 * lane];
            cs0 += v.x; cs1 += v.y; cs2 += v.z; cs3 += v.w;
            float ss = v.x * v.x + v.y * v.y + v.z * v.z + v.w * v.w;
            for (int off = 32; off; off >>= 1) ss += __shfl_down(ss, off);
            if (lane == 0) xsq[r] = ss;
        }
    }
    atomicAdd(&mu_sum[4 * lane + 0], cs0);
    atomicAdd(&mu_sum[4 * lane + 1], cs1);
    atomicAdd(&mu_sum[4 * lane + 2], cs2);
    atomicAdd(&mu_sum[4 * lane + 3], cs3);
}

// ---------------- covX accumulate: acc += X^T X over K-slice ----------------
__global__ __launch_bounds__(256) void covx_kernel(const float* __restrict__ X,
                                                   float* __restrict__ acc_out) {
    __shared__ float Ais[16][64];
    __shared__ float Ajs[16][64];
    int t = threadIdx.x;
    int i0 = blockIdx.x * 64, j0 = blockIdx.y * 64;
    int ks = blockIdx.z * KSLICE;
    int lr = t >> 4, lc = (t & 15) * 4;
    int tx = t & 15, ty = t >> 4;
    float acc[4][4] = {};
    for (int kb = 0; kb < KSLICE; kb += 16) {
        int k = ks + kb + lr;
        if (k < NPTS) {
            float4 vi = *(const float4*)&X[k * DIMD + i0 + lc];
            float4 vj = *(const float4*)&X[k * DIMD + j0 + lc];
            *(float4*)&Ais[lr][lc] = vi;
            *(float4*)&Ajs[lr][lc] = vj;
        } else {
            float4 z = {0.f, 0.f, 0.f, 0.f};
            *(float4*)&Ais[lr][lc] = z;
            *(float4*)&Ajs[lr][lc] = z;
        }
        __syncthreads();
#pragma unroll
        for (int kk = 0; kk < 16; ++kk) {
            float4 a = *(float4*)&Ais[kk][tx * 4];
            float4 b = *(float4*)&Ajs[kk][ty * 4];
            float av[4] = {a.x, a.y, a.z, a.w};
            float bv[4] = {b.x, b.y, b.z, b.w};
#pragma unroll
            for (int m = 0; m < 4; ++m)
#pragma unroll
                for (int n = 0; n < 4; ++n) acc[m][n] += av[m] * bv[n];
        }
        __syncthreads();
    }
#pragma unroll
    for (int m = 0; m < 4; ++m)
#pragma unroll
        for (int n = 0; n < 4; ++n)
            atomicAdd(&acc_out[(i0 + 4 * tx + m) * DIMD + j0 + 4 * ty + n], acc[m][n]);
}

// ---------------- covX finalize ----------------
__global__ __launch_bounds__(256) void covxfin_kernel(float* __restrict__ covX,
                                                      const float* __restrict__ mu_sum,
                                                      float* __restrict__ scal) {
    int idx = blockIdx.x * 256 + threadIdx.x;
    int i = idx >> 8, j = idx & 255;
    const float invN = 1.0f / (float)NPTS;
    float v = covX[idx] * invN - (mu_sum[i] * invN) * (mu_sum[j] * invN) + ((i == j) ? 1e-4f : 0.0f);
    covX[idx] = v;
    if (i == j) atomicAdd(&scal[SC_TRCX], v);
}

// ---------------- generic 256x256x256 matmul, 32x32 tiles ----------------
// mode 0: C = A@B
// mode 1: C = A@B, also atomicAdd sum(C^2) -> scal[SC_FROB]
// mode 2: C = (A^T@B)/256 - mu_i*mu_j + 1e-4*I, trace -> scal[SC_TRCT]
// mode 3: C = 1.5*D - 0.5*(A@B); with gridDim.z==2, z==1 uses (A2,B2,C2,D2)
__global__ __launch_bounds__(256) void mm32_kernel(const float* A, const float* B, float* C, const float* D,
                                                   const float* A2, const float* B2, float* C2, const float* D2,
                                                   int mode, const float* mu, float* scal) {
    if (mode == 3 && blockIdx.z == 1) { A = A2; B = B2; C = C2; D = D2; }
    __shared__ float As[32][32];
    __shared__ float Bs[32][32];
    __shared__ float red[256];
    int t = threadIdx.x;
    int tx = t & 15, ty = t >> 4;
    int i0 = blockIdx.x * 32, j0 = blockIdx.y * 32;
    int lr = t >> 3, lc = (t & 7) * 4;
    float acc[2][2] = {};
    for (int kb = 0; kb < 256; kb += 32) {
        if (mode == 2) {
            float4 v = *(const float4*)&A[(kb + lr) * DIMD + i0 + lc];
            *(float4*)&As[lr][lc] = v;
        } else {
            float4 v = *(const float4*)&A[(i0 + lr) * DIMD + kb + lc];
            As[lc + 0][lr] = v.x; As[lc + 1][lr] = v.y; As[lc + 2][lr] = v.z; As[lc + 3][lr] = v.w;
        }
        {
            float4 v = *(const float4*)&B[(kb + lr) * DIMD + j0 + lc];
            *(float4*)&Bs[lr][lc] = v;
        }
        __syncthreads();
#pragma unroll
        for (int kk = 0; kk < 32; ++kk) {
            float a0 = As[kk][2 * tx], a1 = As[kk][2 * tx + 1];
            float b0 = Bs[kk][2 * ty], b1 = Bs[kk][2 * ty + 1];
            acc[0][0] += a0 * b0; acc[0][1] += a0 * b1;
            acc[1][0] += a1 * b0; acc[1][1] += a1 * b1;
        }
        __syncthreads();
    }
    float fr = 0.f;
#pragma unroll
    for (int ii = 0; ii < 2; ++ii)
#pragma unroll
        for (int jj = 0; jj < 2; ++jj) {
            int i = i0 + 2 * tx + ii, j = j0 + 2 * ty + jj;
            float v = acc[ii][jj];
            if (mode == 2) {
                v = v * (1.0f / 256.0f) - mu[i] * mu[j] + ((i == j) ? 1e-4f : 0.0f);
                if (i == j) atomicAdd(&scal[SC_TRCT], v);
            } else if (mode == 3) {
                v = 1.5f * D[i * DIMD + j] - 0.5f * v;
            }
            C[i * DIMD + j] = v;
            if (mode == 1) fr += v * v;
        }
    if (mode == 1) {
        red[t] = fr; __syncthreads();
        for (int s2 = 128; s2 > 0; s2 >>= 1) { if (t < s2) red[t] += red[t + s2]; __syncthreads(); }
        if (t == 0) atomicAdd(&scal[SC_FROB], red[0]);
    }
}

// ---------------- T stats: mu_T + loss_mean ----------------
__global__ __launch_bounds__(256) void tstats_kernel(const float* __restrict__ Tm,
                                                     const float* __restrict__ mu_sum,
                                                     float* __restrict__ mu_T,
                                                     float* __restrict__ scal) {
    __shared__ float red[256];
    int j = threadIdx.x;
    float s = 0.f;
    for (int b = 0; b < BQ; ++b) s += Tm[b * DIMD + j];
    float mt = s * (1.0f / 256.0f);
    mu_T[j] = mt;
    float d = mt - mu_sum[j] * (1.0f / (float)NPTS);
    red[j] = d * d;
    __syncthreads();
    for (int s2 = 128; s2 > 0; s2 >>= 1) { if (j < s2) red[j] += red[j + s2]; __syncthreads(); }
    if (j == 0) scal[SC_LM] = red[0];
}

// ---------------- init Y = G/||G||_F, Z = I ----------------
__global__ __launch_bounds__(256) void inityz_kernel(const float* __restrict__ G,
                                                     const float* __restrict__ scal,
                                                     float* __restrict__ Y, float* __restrict__ Z) {
    int idx = blockIdx.x * 256 + threadIdx.x;
    float invs = rsqrtf(scal[SC_FROB]);   // 1/sqrt(sum G^2) = 1/||G||_F
    Y[idx] = G[idx] * invs;
    Z[idx] = ((idx >> 8) == (idx & 255)) ? 1.0f : 0.0f;
}

// ---------------- finalize loss_dist ----------------
__global__ __launch_bounds__(256) void findist_kernel(const float* __restrict__ Yfin,
                                                      float* __restrict__ scal) {
    __shared__ float red[256];
    int t = threadIdx.x;
    red[t] = Yfin[t * (DIMD + 1)];
    __syncthreads();
    for (int s2 = 128; s2 > 0; s2 >>= 1) { if (t < s2) red[t] += red[t + s2]; __syncthreads(); }
    if (t == 0) {
        float frobsq = scal[SC_FROB];
        float tr_sqrt = powf(frobsq, 0.25f) * red[0];   // sqrt(s)*trace(Y), s=sqrt(frobsq)
        float lc = scal[SC_TRCX] + scal[SC_TRCT] - 2.0f * tr_sqrt;
        scal[SC_LD] = fmaxf(0.0f, scal[SC_LM] + lc);
    }
}

// ---------------- reg: sum(W^2) ----------------
__global__ __launch_bounds__(256) void reg_kernel(const float* __restrict__ W, float* __restrict__ scal) {
    __shared__ float red[256];
    int t = threadIdx.x;
    float s = 0.f;
    int base = blockIdx.x * 1024;
    for (int m = 0; m < 4; ++m) { float w = W[base + m * 256 + t]; s += w * w; }
    red[t] = s;
    __syncthreads();
    for (int s2 = 128; s2 > 0; s2 >>= 1) { if (t < s2) red[t] += red[t + s2]; __syncthreads(); }
    if (t == 0) atomicAdd(&scal[SC_REG], red[0]);
}

// ---------------- KNN GEMM + per-block top-16 ----------------
__global__ __launch_bounds__(256) void knn_kernel(const float* __restrict__ Tm,
                                                  const float* __restrict__ X,
                                                  const float* __restrict__ xsq,
                                                  float* __restrict__ ck, int* __restrict__ ci) {
    __shared__ float Ts[16][64];
    __shared__ float Xs[16][128];
    __shared__ float kt[64][129];
    __shared__ float tk[16][64];
    __shared__ int   ti[16][64];
    int t = threadIdx.x;
    int p0 = blockIdx.x * PCHUNK, q0 = blockIdx.y * 64;
    int tx = t & 15, ty = t >> 4;
    int a_r = t >> 2, a_c = (t & 3) * 4;
    int b_r = t >> 1, b_c = (t & 1) * 8;
    float acc[4][8] = {};
    for (int kb = 0; kb < 256; kb += 16) {
        {
            float4 v = *(const float4*)&Tm[(q0 + a_r) * DIMD + kb + a_c];
            Ts[a_c + 0][a_r] = v.x; Ts[a_c + 1][a_r] = v.y; Ts[a_c + 2][a_r] = v.z; Ts[a_c + 3][a_r] = v.w;
        }
        {
            int p = p0 + b_r;
            if (p < NPTS) {
                float4 v0 = *(const float4*)&X[p * DIMD + kb + b_c];
                float4 v1 = *(const float4*)&X[p * DIMD + kb + b_c + 4];
                Xs[b_c + 0][b_r] = v0.x; Xs[b_c + 1][b_r] = v0.y; Xs[b_c + 2][b_r] = v0.z; Xs[b_c + 3][b_r] = v0.w;
                Xs[b_c + 4][b_r] = v1.x; Xs[b_c + 5][b_r] = v1.y; Xs[b_c + 6][b_r] = v1.z; Xs[b_c + 7][b_r] = v1.w;
            } else {
                for (int m = 0; m < 8; ++m) Xs[b_c + m][b_r] = 0.0f;
            }
        }
        __syncthreads();
#pragma unroll
        for (int kk = 0; kk < 16; ++kk) {
            float4 a  = *(float4*)&Ts[kk][4 * tx];
            float4 b0 = *(float4*)&Xs[kk][8 * ty];
            float4 b1 = *(float4*)&Xs[kk][8 * ty + 4];
            float av[4] = {a.x, a.y, a.z, a.w};
            float bv[8] = {b0.x, b0.y, b0.z, b0.w, b1.x, b1.y, b1.z, b1.w};
#pragma unroll
            for (int qq = 0; qq < 4; ++qq)
#pragma unroll
                for (int pp = 0; pp < 8; ++pp) acc[qq][pp] += av[qq] * bv[pp];
        }
        __syncthreads();
    }
#pragma unroll
    for (int qq = 0; qq < 4; ++qq)
#pragma unroll
        for (int pp = 0; pp < 8; ++pp) {
            int p = p0 + 8 * ty + pp;
            kt[4 * tx + qq][8 * ty + pp] = (p < NPTS) ? (xsq[p] - 2.0f * acc[qq][pp]) : BIGF;
        }
    __syncthreads();
    if (t < 64) {
        for (int s = 0; s < 16; ++s) { tk[s][t] = BIGF; ti[s][t] = 0x7fffffff; }
        float worst = BIGF; int wslot = 0;
        for (int c = 0; c < PCHUNK; ++c) {
            float key = kt[t][c];
            if (key < worst) {
                tk[wslot][t] = key; ti[wslot][t] = p0 + c;
                worst = tk[0][t]; wslot = 0;
                for (int s = 1; s < 16; ++s)
                    if (tk[s][t] > worst) { worst = tk[s][t]; wslot = s; }
            }
        }
        int base = (q0 + t) * NCAND + blockIdx.x * 16;
        for (int s = 0; s < 16; ++s) { ck[base + s] = tk[s][t]; ci[base + s] = ti[s][t]; }
    }
}

// ---------------- global top-16 merge per query ----------------
__global__ __launch_bounds__(256) void merge_kernel(const float* __restrict__ ck,
                                                    const int* __restrict__ ci,
                                                    int* __restrict__ post_idx) {
    __shared__ float tk[16][256];
    __shared__ int   ti[16][256];
    __shared__ float rk[256];
    __shared__ int   ri[256];
    __shared__ int   rt2[256];
    __shared__ int   rs2[256];
    int q = blockIdx.x, t = threadIdx.x;
    for (int s = 0; s < 16; ++s) { tk[s][t] = BIGF; ti[s][t] = 0x7fffffff; }
    float worst = BIGF; int wslot = 0;
    for (int e = t; e < NCAND; e += 256) {
        float key = ck[q * NCAND + e];
        if (key < worst) {
            tk[wslot][t] = key; ti[wslot][t] = ci[q * NCAND + e];
            worst = tk[0][t]; wslot = 0;
            for (int s = 1; s < 16; ++s)
                if (tk[s][t] > worst) { worst = tk[s][t]; wslot = s; }
        }
    }
    __syncthreads();
    for (int r = 0; r < 16; ++r) {
        float bk = tk[0][t]; int bi = ti[0][t], bs = 0;
        for (int s = 1; s < 16; ++s) {
            float k2 = tk[s][t]; int i2 = ti[s][t];
            if (k2 < bk || (k2 == bk && i2 < bi)) { bk = k2; bi = i2; bs = s; }
        }
        rk[t] = bk; ri[t] = bi; rt2[t] = t; rs2[t] = bs;
        __syncthreads();
        for (int s2 = 128; s2 > 0; s2 >>= 1) {
            if (t < s2) {
                float ko = rk[t + s2]; int io = ri[t + s2];
                if (ko < rk[t] || (ko == rk[t] && io < ri[t])) {
                    rk[t] = ko; ri[t] = io; rt2[t] = rt2[t + s2]; rs2[t] = rs2[t + s2];
                }
            }
            __syncthreads();
        }
        if (t == rt2[0]) { tk[rs2[0]][t] = BIGF; ti[rs2[0]][t] = 0x7fffffff; }
        if (t == 0) post_idx[q * 16 + r] = ri[0];
        __syncthreads();
    }
}

// ---------------- exact l2 + softmax weights ----------------
__global__ __launch_bounds__(256) void l2sm_kernel(const float* __restrict__ Tm,
                                                   const float* __restrict__ X,
                                                   const int* __restrict__ post_idx,
                                                   float* __restrict__ post_w) {
    __shared__ float l2s[16];
    int b = blockIdx.x, t = threadIdx.x;
    int k = t >> 4, j = t & 15;
    int idx = post_idx[b * 16 + k];
    float s = 0.f;
    for (int i = 0; i < 16; ++i) {
        int d = j + 16 * i;
        float df = Tm[b * DIMD + d] - X[idx * DIMD + d];
        s += df * df;
    }
    for (int off = 8; off; off >>= 1) s += __shfl_down(s, off, 16);
    if (j == 0) l2s[k] = s;
    __syncthreads();
    if (t < 16) {
        float x = -l2s[t] * 10.0f;   // -l2 / TAU, TAU = 0.1
        float m = x;
        for (int mm = 8; mm; mm >>= 1) m = fmaxf(m, __shfl_xor(m, mm, 16));
        float e = expf(x - m);
        float ssum = e;
        for (int mm = 8; mm; mm >>= 1) ssum += __shfl_xor(ssum, mm, 16);
        post_w[b * 16 + t] = e / ssum;
    }
}

// ---------------- KL per sample (exact reference semantics) ----------------
__global__ __launch_bounds__(256) void kl_kernel(const int* __restrict__ q_indices,
                                                 const int* __restrict__ pre_indices,
                                                 const float* __restrict__ pre_weights,
                                                 const int* __restrict__ post_idx,
                                                 const float* __restrict__ post_w,
                                                 float* __restrict__ scal) {
    int b = threadIdx.x;
    int qi = q_indices[b];
    int pid[16]; float pw[16]; int sid[16]; float sw[16];
    for (int k = 0; k < 16; ++k) {
        pid[k] = pre_indices[qi * 16 + k];
        pw[k]  = pre_weights[qi * 16 + k];
        sid[k] = post_idx[b * 16 + k];
        sw[k]  = post_w[b * 16 + k];
    }
    float psum = 0.f, qsum = 0.f, kl = 0.f;
    for (int pass = 0; pass < 2; ++pass) {
        for (int i = 0; i < 32; ++i) {
            int c = (i < 16) ? pid[i] : sid[i - 16];
            bool first = true;
            for (int jj = 0; jj < i; ++jj) {
                int cj = (jj < 16) ? pid[jj] : sid[jj - 16];
                if (cj == c) { first = false; break; }
            }
            if (!first) continue;
            float p = 0.f, q = 0.f;
            for (int k2 = 0; k2 < 16; ++k2) {
                if (pid[k2] == c) p += pw[k2];
                if (sid[k2] == c) q += sw[k2];
            }
            p = fmaxf(p, 1e-8f); q = fmaxf(q, 1e-8f);
            if (pass == 0) { psum += p; qsum += q; }
            else {
                float pn = p / psum, qn = q / qsum;
                kl += pn * (logf(pn) - logf(qn));
            }
        }
    }
    atomicAdd(&scal[SC_KNN], kl * (1.0f / 256.0f));
}

// ---------------- final assembly ----------------
__global__ void assemble_kernel(const float* __restrict__ scal, float* __restrict__ out) {
    if (threadIdx.x == 0) {
        float ld = scal[SC_LD], lk = scal[SC_KNN], reg = scal[SC_REG];
        out[0] = ld + lk + 1e-4f * 0.5f * reg;
        out[1] = ld;
        out[2] = lk;
    }
}

extern "C" void kernel_launch(void* const* d_in, const int* in_sizes, int n_in,
                              void* d_out, int out_size, void* d_ws, size_t ws_size,
                              hipStream_t stream) {
    (void)in_sizes; (void)n_in; (void)out_size; (void)ws_size;
    const float* X           = (const float*)d_in[0];
    const float* W           = (const float*)d_in[1];
    const float* q_batch     = (const float*)d_in[2];
    const float* pre_weights = (const float*)d_in[3];
    const int*   q_indices   = (const int*)d_in[4];
    const int*   pre_indices = (const int*)d_in[5];
    float* out = (float*)d_out;
    float* ws  = (float*)d_ws;

    float* mu_sum = ws + 0;
    float* scal   = ws + 256;
    float* mu_T   = ws + 512;
    float* covX   = ws + 1024;
    float* Tm     = ws + 66560;
    float* cov    = ws + 132096;
    float* G      = ws + 197632;
    float* Ya     = ws + 263168;
    float* Za     = ws + 328704;
    float* Yb     = ws + 394240;
    float* Zb     = ws + 459776;
    float* P      = ws + 525312;
    float* xsq    = ws + 590848;
    float* post_w = ws + 691200;
    int*   post_idx = (int*)(ws + 695296);
    float* ck     = ws + 699392;
    int*   ci     = (int*)(ws + 3902464);

    // 0. zero accumulators (mu_sum, scal, covX)
    zero_kernel<<<260, 256, 0, stream>>>(ws);
    // reg term (independent)
    reg_kernel<<<64, 256, 0, stream>>>(W, scal);
    // 1. X stats
    statsx_kernel<<<98, 256, 0, stream>>>(X, xsq, mu_sum);
    // 2. covX
    covx_kernel<<<dim3(4, 4, KSPLIT), 256, 0, stream>>>(X, covX);
    covxfin_kernel<<<256, 256, 0, stream>>>(covX, mu_sum, scal);
    // 3. T = q_batch @ W
    mm32_kernel<<<dim3(8, 8, 1), 256, 0, stream>>>(q_batch, W, Tm, nullptr,
                                                   nullptr, nullptr, nullptr, nullptr, 0, nullptr, scal);
    // 4. T stats + loss_mean
    tstats_kernel<<<1, 256, 0, stream>>>(Tm, mu_sum, mu_T, scal);
    // 5. cov = T^T T /256 - muT muT^T + dI  (+trace)
    mm32_kernel<<<dim3(8, 8, 1), 256, 0, stream>>>(Tm, Tm, cov, nullptr,
                                                   nullptr, nullptr, nullptr, nullptr, 2, mu_T, scal);
    // 6. G = cov @ covX (+frobenius)
    mm32_kernel<<<dim3(8, 8, 1), 256, 0, stream>>>(cov, covX, G, nullptr,
                                                   nullptr, nullptr, nullptr, nullptr, 1, nullptr, scal);
    // 7. Newton-Schulz: trace(sqrt(G))
    inityz_kernel<<<256, 256, 0, stream>>>(G, scal, Ya, Za);
    float *Yc = Ya, *Zc = Za, *Yn = Yb, *Zn = Zb;
    for (int it = 0; it < NS_ITERS; ++it) {
        mm32_kernel<<<dim3(8, 8, 1), 256, 0, stream>>>(Zc, Yc, P, nullptr,
                                                       nullptr, nullptr, nullptr, nullptr, 0, nullptr, scal);
        mm32_kernel<<<dim3(8, 8, 2), 256, 0, stream>>>(Yc, P, Yn, Yc,
                                                       P, Zc, Zn, Zc, 3, nullptr, scal);
        float* ty_ = Yc; Yc = Yn; Yn = ty_;
        float* tz_ = Zc; Zc = Zn; Zn = tz_;
    }
    findist_kernel<<<1, 256, 0, stream>>>(Yc, scal);
    // 8. KNN: distances + block top-16, then global merge
    knn_kernel<<<dim3(NPCH, 4, 1), 256, 0, stream>>>(Tm, X, xsq, ck, ci);
    merge_kernel<<<256, 256, 0, stream>>>(ck, ci, post_idx);
    // 9. exact l2 + softmax
    l2sm_kernel<<<256, 256, 0, stream>>>(Tm, X, post_idx, post_w);
    // 10. KL
    kl_kernel<<<1, 256, 0, stream>>>(q_indices, pre_indices, pre_weights, post_idx, post_w, scal);
    // 11. assemble outputs
    assemble_kernel<<<1, 64, 0, stream>>>(scal, out);
}